// Round 13
// baseline (221.006 us; speedup 1.0000x reference)
//
#include <hip/hip_runtime.h>
#include <hip/hip_bf16.h>

#define DFEAT 128
#define RSPLIT 8    // node-range splits (LDS hist = 2*ceil(N/8)*4 B = 50 KB)
#define SSPLIT 64   // edge-slice splits (grid = 512 blocks)

typedef __attribute__((ext_vector_type(8))) short short8;
typedef __attribute__((ext_vector_type(4))) float f32x4;

__device__ __forceinline__ ushort f2bf(float f) {
    uint u = __float_as_uint(f);
    u += 0x7FFF + ((u >> 16) & 1);   // round-to-nearest-even
    return (ushort)(u >> 16);
}
__device__ __forceinline__ float bf_lo(uint v) { return __uint_as_float(v << 16); }
__device__ __forceinline__ float bf_hi(uint v) { return __uint_as_float(v & 0xFFFF0000u); }

// ---------------- CSR build (zero global atomics) ----------------

// Block (r,s): LDS-privatized dst & src histograms for node range r over edge
// slice s. Captures per-edge rank within (dst, slice) from the LDS atomic.
// Partial tables + ranks stored as ushort (counts << 65536).
// Also fused: W-transpose prep (each block converts 96 Wtb elements).
__global__ __launch_bounds__(512) void histrank_kernel(const int* __restrict__ EI,
                                                       ushort* __restrict__ cnt_part,
                                                       ushort* __restrict__ deg_part,
                                                       ushort* __restrict__ erank,
                                                       const float* __restrict__ W0,
                                                       const float* __restrict__ W1,
                                                       const float* __restrict__ W2,
                                                       ushort* __restrict__ Wtb,
                                                       int nedges, int nnodes,
                                                       int range, int slice) {
    extern __shared__ int lds[];      // [0,range): dst hist, [range,2*range): src hist
    int* hd = lds;
    int* hs = lds + range;
    const int r = blockIdx.x & (RSPLIT - 1);
    const int s = blockIdx.x / RSPLIT;
    const int base = r * range;

    // fused prepw: 512 blocks x 96 elems = 49152 = 3*128*128
    if (threadIdx.x < 96) {
        int i = blockIdx.x * 96 + threadIdx.x;
        int m = i >> 14, rr = i & 16383;
        int n = rr >> 7, k = rr & 127;
        const float* W = (m == 0) ? W0 : (m == 1) ? W1 : W2;
        Wtb[i] = f2bf(W[k * DFEAT + n]);
    }

    for (int i = threadIdx.x; i < 2 * range; i += 512) lds[i] = 0;
    __syncthreads();

    const int e0 = s * slice;
    const int e1 = min(nedges, e0 + slice);
    for (int e = e0 + threadIdx.x; e < e1; e += 512) {
        int dst = EI[e];
        int src = EI[nedges + e];
        unsigned ud = (unsigned)(dst - base);
        unsigned us = (unsigned)(src - base);
        if (ud < (unsigned)range) erank[e] = (ushort)atomicAdd(&hd[ud], 1);
        if (us < (unsigned)range) atomicAdd(&hs[us], 1);
    }
    __syncthreads();

    for (int i = threadIdx.x; i < range; i += 512) {
        int node = base + i;
        if (node < nnodes) {
            cnt_part[s * nnodes + node] = (ushort)hd[i];
            deg_part[s * nnodes + node] = (ushort)hs[i];
        }
    }
}

// Per node: in-place exclusive prefix over the SSPLIT cnt partials (cnt_part
// becomes the slice-prefix table), sum deg partials -> dis, then block-scan
// the node totals into offs[g+1] + bsums.
__global__ __launch_bounds__(1024) void scan1_kernel(ushort* __restrict__ cnt_part,
                                                     const ushort* __restrict__ deg_part,
                                                     int* __restrict__ offs,
                                                     int* __restrict__ bsums,
                                                     float* __restrict__ dis, int n) {
    __shared__ int sm[1024];
    int t = threadIdx.x;
    int g = blockIdx.x * 1024 + t;
    int c = 0;
    if (g < n) {
        int d = 0;
        #pragma unroll
        for (int s = 0; s < SSPLIT; ++s) {
            int v = cnt_part[s * n + g];
            cnt_part[s * n + g] = (ushort)c;   // exclusive slice prefix, in place
            c += v;
            d += deg_part[s * n + g];
        }
        dis[g] = (d > 0) ? rsqrtf((float)d) : 0.0f;
    }
    sm[t] = c;
    __syncthreads();
    for (int off = 1; off < 1024; off <<= 1) {
        int add = (t >= off) ? sm[t - off] : 0;
        __syncthreads();
        sm[t] += add;
        __syncthreads();
    }
    if (g < n) offs[g + 1] = sm[t];
    if (t == 1023) bsums[blockIdx.x] = sm[1023];
}

// scan3 with fused block-sum scan: every block redundantly exclusive-scans
// bsums[0..nb) (nb <= 64) in its first wave, then adds to its slice.
__global__ __launch_bounds__(1024) void scan3_kernel(int* __restrict__ offs,
                                                     const int* __restrict__ bsums,
                                                     int n, int nb) {
    __shared__ int pre[64];
    int t = threadIdx.x;
    if (t < 64) {
        int v = (t < nb) ? bsums[t] : 0;
        for (int off = 1; off < 64; off <<= 1) {
            int u = __shfl_up(v, off);
            if (t >= off) v += u;
        }
        int ex = __shfl_up(v, 1);
        if (t == 0) ex = 0;
        pre[t] = ex;
    }
    __syncthreads();
    int add = pre[blockIdx.x];
    int g = blockIdx.x * 1024 + t;
    if (g < n) offs[g + 1] += add;
    if (blockIdx.x == 0 && t == 0) offs[0] = 0;
}

// Atomic-free fill: slot = offs[dst] + sprefix[slice][dst] + local rank.
// esrc scatter uses nontemporal stores (write-once, no reuse before agg).
__global__ void fill_kernel(const int* __restrict__ EI, const int* __restrict__ offs,
                            const ushort* __restrict__ erank,
                            const ushort* __restrict__ sprefix,
                            int* __restrict__ esrc, int nedges, int nnodes, int slice) {
    int e = blockIdx.x * blockDim.x + threadIdx.x;
    if (e >= nedges) return;
    int dst = EI[e];
    int src = EI[nedges + e];
    int s = e / slice;
    int idx = offs[dst] + (int)sprefix[s * nnodes + dst] + (int)erank[e];
    __builtin_nontemporal_store(src, &esrc[idx]);
}

// ---------------- GEMM: Hd[N,128](bf16) = dis[r] * (Xin[N,128] @ W) --------
// MFMA 16x16x32 bf16. 128 rows/block (4 waves x 2 row-tiles), Wt in LDS,
// one ds_read_b128 feeds 2 MFMAs (B-register reuse across row-tiles).

template <int IN_F32>
__global__ __launch_bounds__(256) void gemm_mfma(const void* __restrict__ Xin,
                                                 const ushort* __restrict__ Wtb,
                                                 const float* __restrict__ dis,
                                                 ushort* __restrict__ Hb, int nrows) {
    __shared__ ushort wlds[128 * 136];
    const int t = threadIdx.x;

    #pragma unroll
    for (int q = 0; q < 8; ++q) {
        int c = t + q * 256;
        int row = c >> 4, cr = c & 15;
        short8 v = *(const short8*)(Wtb + c * 8);
        *(short8*)(&wlds[row * 136 + cr * 8]) = v;
    }

    const int lane = t & 63;
    const int r16 = lane & 15, g = lane >> 4;
    const int wv = t >> 6;
    const int rbase = blockIdx.x * 128 + wv * 16;

    // A fragments for both row-tiles (global loads overlap LDS staging)
    short8 a[2][4];
    #pragma unroll
    for (int rt = 0; rt < 2; ++rt) {
        int row = rbase + rt * 64 + r16;
        int srow = (row < nrows) ? row : (nrows - 1);
        if (IN_F32) {
            const float* X = (const float*)Xin;
            #pragma unroll
            for (int kc = 0; kc < 4; ++kc) {
                const float* p = X + (size_t)srow * DFEAT + kc * 32 + g * 8;
                float4 f0 = *(const float4*)p;
                float4 f1 = *(const float4*)(p + 4);
                short8 sv;
                sv[0] = (short)f2bf(f0.x); sv[1] = (short)f2bf(f0.y);
                sv[2] = (short)f2bf(f0.z); sv[3] = (short)f2bf(f0.w);
                sv[4] = (short)f2bf(f1.x); sv[5] = (short)f2bf(f1.y);
                sv[6] = (short)f2bf(f1.z); sv[7] = (short)f2bf(f1.w);
                a[rt][kc] = sv;
            }
        } else {
            const ushort* X = (const ushort*)Xin;
            #pragma unroll
            for (int kc = 0; kc < 4; ++kc)
                a[rt][kc] = *(const short8*)(X + (size_t)srow * DFEAT + kc * 32 + g * 8);
        }
    }
    __syncthreads();

    f32x4 acc[2][8];
    #pragma unroll
    for (int rt = 0; rt < 2; ++rt)
        #pragma unroll
        for (int nt = 0; nt < 8; ++nt) acc[rt][nt] = (f32x4){0.f, 0.f, 0.f, 0.f};

    #pragma unroll
    for (int kc = 0; kc < 4; ++kc) {
        #pragma unroll
        for (int nt = 0; nt < 8; ++nt) {
            short8 b = *(const short8*)(&wlds[(nt * 16 + r16) * 136 + kc * 32 + g * 8]);
            acc[0][nt] = __builtin_amdgcn_mfma_f32_16x16x32_bf16(a[0][kc], b, acc[0][nt], 0, 0, 0);
            acc[1][nt] = __builtin_amdgcn_mfma_f32_16x16x32_bf16(a[1][kc], b, acc[1][nt], 0, 0, 0);
        }
    }

    #pragma unroll
    for (int rt = 0; rt < 2; ++rt) {
        const int orow_base = rbase + rt * 64 + g * 4;
        #pragma unroll
        for (int r = 0; r < 4; ++r) {
            int orow = orow_base + r;
            if (orow < nrows) {
                float d = dis[orow];
                #pragma unroll
                for (int nt = 0; nt < 8; ++nt)
                    Hb[(size_t)orow * DFEAT + nt * 16 + r16] = f2bf(acc[rt][nt][r] * d);
            }
        }
    }
}

// ------- Aggregation: one wave per dst node, broadcast-index gathers -------
// 64 lanes load esrc[s+base+lane] coalesced (64 edges/batch); indices are
// broadcast to quarters via wave-uniform __shfl (no divergent shfl -- R9
// lesson); validity via mask-multiply fmaf. Quarter q = lane>>4 owns chunk
// [q*clen,(q+1)*clen); feats 8*(l16)..+7 (uint4 = 16 B/lane). Inner loop
// issues 8 independent gathers -> up to 32 edges in flight per wave.

template <int RELU, int OUT_F32>
__global__ __launch_bounds__(256) void agg_kernel(const ushort* __restrict__ H,
                                                  const int* __restrict__ offs,
                                                  const int* __restrict__ esrc,
                                                  const float* __restrict__ dis,
                                                  const float* __restrict__ bias,
                                                  void* __restrict__ OUT, int nnodes) {
    int node = blockIdx.x * 4 + (threadIdx.x >> 6);
    if (node >= nnodes) return;
    int lane = threadIdx.x & 63;
    int q = lane >> 4;
    int l16 = lane & 15;
    int s = offs[node];
    int deg = offs[node + 1] - s;

    float a0 = 0.f, a1 = 0.f, a2 = 0.f, a3 = 0.f;
    float a4 = 0.f, a5 = 0.f, a6 = 0.f, a7 = 0.f;
    float c0 = 0.f, c1 = 0.f, c2 = 0.f, c3 = 0.f;
    float c4 = 0.f, c5 = 0.f, c6 = 0.f, c7 = 0.f;
    const ushort* __restrict__ Hp = H + l16 * 8;

    for (int base = 0; base < deg; base += 64) {
        int rem = deg - base;
        int cnt = (rem < 64) ? rem : 64;
        int idx = (base + lane < deg) ? esrc[s + base + lane] : 0;
        int clen = (cnt + 3) >> 2;        // wave-uniform chunk length (<=16)
        int jbase = q * clen;
        for (int jj = 0; jj < clen; jj += 8) {   // wave-uniform trip count
            int j0 = jbase + jj;
            // all shfls unconditional, all 64 lanes active (4*clen-1 <= 63)
            int s0 = __shfl(idx, j0);
            int s1 = __shfl(idx, j0 + 1);
            int s2 = __shfl(idx, j0 + 2);
            int s3 = __shfl(idx, j0 + 3);
            int s4 = __shfl(idx, (j0 + 4) & 63);
            int s5 = __shfl(idx, (j0 + 5) & 63);
            int s6 = __shfl(idx, (j0 + 6) & 63);
            int s7 = __shfl(idx, (j0 + 7) & 63);
            float m0 = (jj < clen && j0 < cnt) ? 1.f : 0.f;
            float m1 = (jj + 1 < clen && j0 + 1 < cnt) ? 1.f : 0.f;
            float m2 = (jj + 2 < clen && j0 + 2 < cnt) ? 1.f : 0.f;
            float m3 = (jj + 3 < clen && j0 + 3 < cnt) ? 1.f : 0.f;
            float m4 = (jj + 4 < clen && j0 + 4 < cnt) ? 1.f : 0.f;
            float m5 = (jj + 5 < clen && j0 + 5 < cnt) ? 1.f : 0.f;
            float m6 = (jj + 6 < clen && j0 + 6 < cnt) ? 1.f : 0.f;
            float m7 = (jj + 7 < clen && j0 + 7 < cnt) ? 1.f : 0.f;
            uint4 v0 = *(const uint4*)(Hp + (size_t)s0 * DFEAT);
            uint4 v1 = *(const uint4*)(Hp + (size_t)s1 * DFEAT);
            uint4 v2 = *(const uint4*)(Hp + (size_t)s2 * DFEAT);
            uint4 v3 = *(const uint4*)(Hp + (size_t)s3 * DFEAT);
            uint4 v4 = *(const uint4*)(Hp + (size_t)s4 * DFEAT);
            uint4 v5 = *(const uint4*)(Hp + (size_t)s5 * DFEAT);
            uint4 v6 = *(const uint4*)(Hp + (size_t)s6 * DFEAT);
            uint4 v7 = *(const uint4*)(Hp + (size_t)s7 * DFEAT);
            a0 = fmaf(m0, bf_lo(v0.x), a0); a1 = fmaf(m0, bf_hi(v0.x), a1);
            a2 = fmaf(m0, bf_lo(v0.y), a2); a3 = fmaf(m0, bf_hi(v0.y), a3);
            a4 = fmaf(m0, bf_lo(v0.z), a4); a5 = fmaf(m0, bf_hi(v0.z), a5);
            a6 = fmaf(m0, bf_lo(v0.w), a6); a7 = fmaf(m0, bf_hi(v0.w), a7);
            c0 = fmaf(m1, bf_lo(v1.x), c0); c1 = fmaf(m1, bf_hi(v1.x), c1);
            c2 = fmaf(m1, bf_lo(v1.y), c2); c3 = fmaf(m1, bf_hi(v1.y), c3);
            c4 = fmaf(m1, bf_lo(v1.z), c4); c5 = fmaf(m1, bf_hi(v1.z), c5);
            c6 = fmaf(m1, bf_lo(v1.w), c6); c7 = fmaf(m1, bf_hi(v1.w), c7);
            a0 = fmaf(m2, bf_lo(v2.x), a0); a1 = fmaf(m2, bf_hi(v2.x), a1);
            a2 = fmaf(m2, bf_lo(v2.y), a2); a3 = fmaf(m2, bf_hi(v2.y), a3);
            a4 = fmaf(m2, bf_lo(v2.z), a4); a5 = fmaf(m2, bf_hi(v2.z), a5);
            a6 = fmaf(m2, bf_lo(v2.w), a6); a7 = fmaf(m2, bf_hi(v2.w), a7);
            c0 = fmaf(m3, bf_lo(v3.x), c0); c1 = fmaf(m3, bf_hi(v3.x), c1);
            c2 = fmaf(m3, bf_lo(v3.y), c2); c3 = fmaf(m3, bf_hi(v3.y), c3);
            c4 = fmaf(m3, bf_lo(v3.z), c4); c5 = fmaf(m3, bf_hi(v3.z), c5);
            c6 = fmaf(m3, bf_lo(v3.w), c6); c7 = fmaf(m3, bf_hi(v3.w), c7);
            a0 = fmaf(m4, bf_lo(v4.x), a0); a1 = fmaf(m4, bf_hi(v4.x), a1);
            a2 = fmaf(m4, bf_lo(v4.y), a2); a3 = fmaf(m4, bf_hi(v4.y), a3);
            a4 = fmaf(m4, bf_lo(v4.z), a4); a5 = fmaf(m4, bf_hi(v4.z), a5);
            a6 = fmaf(m4, bf_lo(v4.w), a6); a7 = fmaf(m4, bf_hi(v4.w), a7);
            c0 = fmaf(m5, bf_lo(v5.x), c0); c1 = fmaf(m5, bf_hi(v5.x), c1);
            c2 = fmaf(m5, bf_lo(v5.y), c2); c3 = fmaf(m5, bf_hi(v5.y), c3);
            c4 = fmaf(m5, bf_lo(v5.z), c4); c5 = fmaf(m5, bf_hi(v5.z), c5);
            c6 = fmaf(m5, bf_lo(v5.w), c6); c7 = fmaf(m5, bf_hi(v5.w), c7);
            a0 = fmaf(m6, bf_lo(v6.x), a0); a1 = fmaf(m6, bf_hi(v6.x), a1);
            a2 = fmaf(m6, bf_lo(v6.y), a2); a3 = fmaf(m6, bf_hi(v6.y), a3);
            a4 = fmaf(m6, bf_lo(v6.z), a4); a5 = fmaf(m6, bf_hi(v6.z), a5);
            a6 = fmaf(m6, bf_lo(v6.w), a6); a7 = fmaf(m6, bf_hi(v6.w), a7);
            c0 = fmaf(m7, bf_lo(v7.x), c0); c1 = fmaf(m7, bf_hi(v7.x), c1);
            c2 = fmaf(m7, bf_lo(v7.y), c2); c3 = fmaf(m7, bf_hi(v7.y), c3);
            c4 = fmaf(m7, bf_lo(v7.z), c4); c5 = fmaf(m7, bf_hi(v7.z), c5);
            c6 = fmaf(m7, bf_lo(v7.w), c6); c7 = fmaf(m7, bf_hi(v7.w), c7);
        }
    }
    a0 += c0; a1 += c1; a2 += c2; a3 += c3;
    a4 += c4; a5 += c5; a6 += c6; a7 += c7;

    a0 += __shfl_xor(a0, 16); a1 += __shfl_xor(a1, 16);
    a2 += __shfl_xor(a2, 16); a3 += __shfl_xor(a3, 16);
    a4 += __shfl_xor(a4, 16); a5 += __shfl_xor(a5, 16);
    a6 += __shfl_xor(a6, 16); a7 += __shfl_xor(a7, 16);
    a0 += __shfl_xor(a0, 32); a1 += __shfl_xor(a1, 32);
    a2 += __shfl_xor(a2, 32); a3 += __shfl_xor(a3, 32);
    a4 += __shfl_xor(a4, 32); a5 += __shfl_xor(a5, 32);
    a6 += __shfl_xor(a6, 32); a7 += __shfl_xor(a7, 32);

    float dn = dis[node];
    float4 b0 = *(const float4*)&bias[l16 * 8];
    float4 b1 = *(const float4*)&bias[l16 * 8 + 4];
    float r0 = dn * a0 + b0.x, r1 = dn * a1 + b0.y;
    float r2 = dn * a2 + b0.z, r3 = dn * a3 + b0.w;
    float r4 = dn * a4 + b1.x, r5 = dn * a5 + b1.y;
    float r6 = dn * a6 + b1.z, r7 = dn * a7 + b1.w;
    if (RELU) {
        r0 = fmaxf(r0, 0.f); r1 = fmaxf(r1, 0.f);
        r2 = fmaxf(r2, 0.f); r3 = fmaxf(r3, 0.f);
        r4 = fmaxf(r4, 0.f); r5 = fmaxf(r5, 0.f);
        r6 = fmaxf(r6, 0.f); r7 = fmaxf(r7, 0.f);
    }
    if (q == 0) {
        if (OUT_F32) {
            float* o = (float*)OUT + (size_t)node * DFEAT + l16 * 8;
            __builtin_nontemporal_store((f32x4){r0, r1, r2, r3}, (f32x4*)o);
            __builtin_nontemporal_store((f32x4){r4, r5, r6, r7}, (f32x4*)(o + 4));
        } else {
            uint4 p;
            p.x = (uint)f2bf(r0) | ((uint)f2bf(r1) << 16);
            p.y = (uint)f2bf(r2) | ((uint)f2bf(r3) << 16);
            p.z = (uint)f2bf(r4) | ((uint)f2bf(r5) << 16);
            p.w = (uint)f2bf(r6) | ((uint)f2bf(r7) << 16);
            *(uint4*)((ushort*)OUT + (size_t)node * DFEAT + l16 * 8) = p;
        }
    }
}

// ---------------- launch ----------------

extern "C" void kernel_launch(void* const* d_in, const int* in_sizes, int n_in,
                              void* d_out, int out_size, void* d_ws, size_t ws_size,
                              hipStream_t stream) {
    const float* x  = (const float*)d_in[0];
    const int*   EI = (const int*)d_in[1];
    const float* W0 = (const float*)d_in[2];
    const float* b0 = (const float*)d_in[3];
    const float* W1 = (const float*)d_in[4];
    const float* b1 = (const float*)d_in[5];
    const float* W2 = (const float*)d_in[6];
    const float* b2 = (const float*)d_in[7];
    float* out = (float*)d_out;

    const int N = in_sizes[0] / DFEAT;
    const int E = in_sizes[1] / 2;
    const int range = (N + RSPLIT - 1) / RSPLIT;
    const int slice = (E + SSPLIT - 1) / SSPLIT;

    // workspace layout (256B aligned)
    char* w = (char*)d_ws;
    auto alloc = [&](size_t bytes) {
        void* p = (void*)w;
        w += (bytes + 255) & ~(size_t)255;
        return p;
    };
    int*    offs  = (int*)alloc((size_t)(N + 1) * 4);
    int*    bsums = (int*)alloc(64 * 4);
    float*  dis   = (float*)alloc((size_t)N * 4);
    ushort* erank = (ushort*)alloc((size_t)E * 2);
    int*    esrc  = (int*)alloc((size_t)E * 4);
    ushort* Wtb   = (ushort*)alloc((size_t)3 * DFEAT * DFEAT * 2);
    ushort* hbuf  = (ushort*)alloc((size_t)N * DFEAT * 2);
    ushort* abuf  = (ushort*)alloc((size_t)N * DFEAT * 2);

    // CSR-build scratch aliased onto hbuf/abuf (dead before gemm/agg run):
    // SSPLIT*N ushorts = 6.4 MB <= N*DFEAT*2 = 12.8 MB.
    ushort* cnt_part = (ushort*)hbuf;   // becomes slice-prefix table after scan1
    ushort* deg_part = (ushort*)abuf;

    const int nb = (N + 1023) / 1024;

    histrank_kernel<<<RSPLIT * SSPLIT, 512, 2 * range * 4, stream>>>(
        EI, cnt_part, deg_part, erank, W0, W1, W2, Wtb, E, N, range, slice);
    scan1_kernel<<<nb, 1024, 0, stream>>>(cnt_part, deg_part, offs, bsums, dis, N);
    scan3_kernel<<<nb, 1024, 0, stream>>>(offs, bsums, N, nb);
    fill_kernel<<<(E + 255) / 256, 256, 0, stream>>>(EI, offs, erank, cnt_part,
                                                     esrc, E, N, slice);

    const int gemmGrid = (N + 127) / 128;
    const int aggGrid  = (N + 3) / 4;

    // layer 0: x(f32) -> hbuf(bf16, dis-scaled) -> abuf(bf16, relu)
    gemm_mfma<1><<<gemmGrid, 256, 0, stream>>>(x, Wtb, dis, hbuf, N);
    agg_kernel<1, 0><<<aggGrid, 256, 0, stream>>>(hbuf, offs, esrc, dis, b0, abuf, N);
    // layer 1
    gemm_mfma<0><<<gemmGrid, 256, 0, stream>>>(abuf, Wtb + DFEAT * DFEAT, dis, hbuf, N);
    agg_kernel<1, 0><<<aggGrid, 256, 0, stream>>>(hbuf, offs, esrc, dis, b1, abuf, N);
    // layer 2: -> d_out (f32, no relu)
    gemm_mfma<0><<<gemmGrid, 256, 0, stream>>>(abuf, Wtb + 2 * DFEAT * DFEAT, dis, hbuf, N);
    agg_kernel<0, 1><<<aggGrid, 256, 0, stream>>>(hbuf, offs, esrc, dis, b2, out, N);
}

// Round 14
// 187.777 us; speedup vs baseline: 1.1770x; 1.1770x over previous
//
#include <hip/hip_runtime.h>
#include <hip/hip_bf16.h>

#define DFEAT 128
#define RSPLIT 8    // node-range splits (LDS hist = 2*ceil(N/8)*4 B = 50 KB)
#define SSPLIT 64   // edge-slice splits (grid = 512 blocks)

typedef __attribute__((ext_vector_type(8))) short short8;
typedef __attribute__((ext_vector_type(4))) float f32x4;

__device__ __forceinline__ ushort f2bf(float f) {
    uint u = __float_as_uint(f);
    u += 0x7FFF + ((u >> 16) & 1);   // round-to-nearest-even
    return (ushort)(u >> 16);
}
__device__ __forceinline__ float bf_lo(uint v) { return __uint_as_float(v << 16); }
__device__ __forceinline__ float bf_hi(uint v) { return __uint_as_float(v & 0xFFFF0000u); }

// ---------------- CSR build (zero global atomics) ----------------

// Block (r,s): LDS-privatized dst & src histograms for node range r over edge
// slice s. Captures per-edge rank within (dst, slice) from the LDS atomic.
// Partial tables + ranks stored as ushort (counts << 65536).
// Also fused: W-transpose prep (each block converts 96 Wtb elements).
__global__ __launch_bounds__(512) void histrank_kernel(const int* __restrict__ EI,
                                                       ushort* __restrict__ cnt_part,
                                                       ushort* __restrict__ deg_part,
                                                       ushort* __restrict__ erank,
                                                       const float* __restrict__ W0,
                                                       const float* __restrict__ W1,
                                                       const float* __restrict__ W2,
                                                       ushort* __restrict__ Wtb,
                                                       int nedges, int nnodes,
                                                       int range, int slice) {
    extern __shared__ int lds[];      // [0,range): dst hist, [range,2*range): src hist
    int* hd = lds;
    int* hs = lds + range;
    const int r = blockIdx.x & (RSPLIT - 1);
    const int s = blockIdx.x / RSPLIT;
    const int base = r * range;

    // fused prepw: 512 blocks x 96 elems = 49152 = 3*128*128
    if (threadIdx.x < 96) {
        int i = blockIdx.x * 96 + threadIdx.x;
        int m = i >> 14, rr = i & 16383;
        int n = rr >> 7, k = rr & 127;
        const float* W = (m == 0) ? W0 : (m == 1) ? W1 : W2;
        Wtb[i] = f2bf(W[k * DFEAT + n]);
    }

    for (int i = threadIdx.x; i < 2 * range; i += 512) lds[i] = 0;
    __syncthreads();

    const int e0 = s * slice;
    const int e1 = min(nedges, e0 + slice);
    for (int e = e0 + threadIdx.x; e < e1; e += 512) {
        int dst = EI[e];
        int src = EI[nedges + e];
        unsigned ud = (unsigned)(dst - base);
        unsigned us = (unsigned)(src - base);
        if (ud < (unsigned)range) erank[e] = (ushort)atomicAdd(&hd[ud], 1);
        if (us < (unsigned)range) atomicAdd(&hs[us], 1);
    }
    __syncthreads();

    for (int i = threadIdx.x; i < range; i += 512) {
        int node = base + i;
        if (node < nnodes) {
            cnt_part[s * nnodes + node] = (ushort)hd[i];
            deg_part[s * nnodes + node] = (ushort)hs[i];
        }
    }
}

// Per node: in-place exclusive prefix over the SSPLIT cnt partials (cnt_part
// becomes the slice-prefix table), sum deg partials -> dis, then block-scan
// the node totals into offs[g+1] + bsums.
__global__ __launch_bounds__(1024) void scan1_kernel(ushort* __restrict__ cnt_part,
                                                     const ushort* __restrict__ deg_part,
                                                     int* __restrict__ offs,
                                                     int* __restrict__ bsums,
                                                     float* __restrict__ dis, int n) {
    __shared__ int sm[1024];
    int t = threadIdx.x;
    int g = blockIdx.x * 1024 + t;
    int c = 0;
    if (g < n) {
        int d = 0;
        #pragma unroll
        for (int s = 0; s < SSPLIT; ++s) {
            int v = cnt_part[s * n + g];
            cnt_part[s * n + g] = (ushort)c;   // exclusive slice prefix, in place
            c += v;
            d += deg_part[s * n + g];
        }
        dis[g] = (d > 0) ? rsqrtf((float)d) : 0.0f;
    }
    sm[t] = c;
    __syncthreads();
    for (int off = 1; off < 1024; off <<= 1) {
        int add = (t >= off) ? sm[t - off] : 0;
        __syncthreads();
        sm[t] += add;
        __syncthreads();
    }
    if (g < n) offs[g + 1] = sm[t];
    if (t == 1023) bsums[blockIdx.x] = sm[1023];
}

// scan3 with fused block-sum scan: every block redundantly exclusive-scans
// bsums[0..nb) (nb <= 64) in its first wave, then adds to its slice.
__global__ __launch_bounds__(1024) void scan3_kernel(int* __restrict__ offs,
                                                     const int* __restrict__ bsums,
                                                     int n, int nb) {
    __shared__ int pre[64];
    int t = threadIdx.x;
    if (t < 64) {
        int v = (t < nb) ? bsums[t] : 0;
        for (int off = 1; off < 64; off <<= 1) {
            int u = __shfl_up(v, off);
            if (t >= off) v += u;
        }
        int ex = __shfl_up(v, 1);
        if (t == 0) ex = 0;
        pre[t] = ex;
    }
    __syncthreads();
    int add = pre[blockIdx.x];
    int g = blockIdx.x * 1024 + t;
    if (g < n) offs[g + 1] += add;
    if (blockIdx.x == 0 && t == 0) offs[0] = 0;
}

// Atomic-free fill: slot = offs[dst] + sprefix[slice][dst] + local rank.
__global__ void fill_kernel(const int* __restrict__ EI, const int* __restrict__ offs,
                            const ushort* __restrict__ erank,
                            const ushort* __restrict__ sprefix,
                            int* __restrict__ esrc, int nedges, int nnodes, int slice) {
    int e = blockIdx.x * blockDim.x + threadIdx.x;
    if (e >= nedges) return;
    int dst = EI[e];
    int src = EI[nedges + e];
    int s = e / slice;
    int idx = offs[dst] + (int)sprefix[s * nnodes + dst] + (int)erank[e];
    esrc[idx] = src;
}

// ---------------- GEMM: Hd[N,128](bf16) = dis[r] * (Xin[N,128] @ W) --------
// MFMA 16x16x32 bf16. 128 rows/block (4 waves x 2 row-tiles), Wt in LDS,
// one ds_read_b128 feeds 2 MFMAs (B-register reuse across row-tiles).

template <int IN_F32>
__global__ __launch_bounds__(256) void gemm_mfma(const void* __restrict__ Xin,
                                                 const ushort* __restrict__ Wtb,
                                                 const float* __restrict__ dis,
                                                 ushort* __restrict__ Hb, int nrows) {
    __shared__ ushort wlds[128 * 136];
    const int t = threadIdx.x;

    #pragma unroll
    for (int q = 0; q < 8; ++q) {
        int c = t + q * 256;
        int row = c >> 4, cr = c & 15;
        short8 v = *(const short8*)(Wtb + c * 8);
        *(short8*)(&wlds[row * 136 + cr * 8]) = v;
    }

    const int lane = t & 63;
    const int r16 = lane & 15, g = lane >> 4;
    const int wv = t >> 6;
    const int rbase = blockIdx.x * 128 + wv * 16;

    // A fragments for both row-tiles (global loads overlap LDS staging)
    short8 a[2][4];
    #pragma unroll
    for (int rt = 0; rt < 2; ++rt) {
        int row = rbase + rt * 64 + r16;
        int srow = (row < nrows) ? row : (nrows - 1);
        if (IN_F32) {
            const float* X = (const float*)Xin;
            #pragma unroll
            for (int kc = 0; kc < 4; ++kc) {
                const float* p = X + (size_t)srow * DFEAT + kc * 32 + g * 8;
                float4 f0 = *(const float4*)p;
                float4 f1 = *(const float4*)(p + 4);
                short8 sv;
                sv[0] = (short)f2bf(f0.x); sv[1] = (short)f2bf(f0.y);
                sv[2] = (short)f2bf(f0.z); sv[3] = (short)f2bf(f0.w);
                sv[4] = (short)f2bf(f1.x); sv[5] = (short)f2bf(f1.y);
                sv[6] = (short)f2bf(f1.z); sv[7] = (short)f2bf(f1.w);
                a[rt][kc] = sv;
            }
        } else {
            const ushort* X = (const ushort*)Xin;
            #pragma unroll
            for (int kc = 0; kc < 4; ++kc)
                a[rt][kc] = *(const short8*)(X + (size_t)srow * DFEAT + kc * 32 + g * 8);
        }
    }
    __syncthreads();

    f32x4 acc[2][8];
    #pragma unroll
    for (int rt = 0; rt < 2; ++rt)
        #pragma unroll
        for (int nt = 0; nt < 8; ++nt) acc[rt][nt] = (f32x4){0.f, 0.f, 0.f, 0.f};

    #pragma unroll
    for (int kc = 0; kc < 4; ++kc) {
        #pragma unroll
        for (int nt = 0; nt < 8; ++nt) {
            short8 b = *(const short8*)(&wlds[(nt * 16 + r16) * 136 + kc * 32 + g * 8]);
            acc[0][nt] = __builtin_amdgcn_mfma_f32_16x16x32_bf16(a[0][kc], b, acc[0][nt], 0, 0, 0);
            acc[1][nt] = __builtin_amdgcn_mfma_f32_16x16x32_bf16(a[1][kc], b, acc[1][nt], 0, 0, 0);
        }
    }

    #pragma unroll
    for (int rt = 0; rt < 2; ++rt) {
        const int orow_base = rbase + rt * 64 + g * 4;
        #pragma unroll
        for (int r = 0; r < 4; ++r) {
            int orow = orow_base + r;
            if (orow < nrows) {
                float d = dis[orow];
                #pragma unroll
                for (int nt = 0; nt < 8; ++nt)
                    Hb[(size_t)orow * DFEAT + nt * 16 + r16] = f2bf(acc[rt][nt][r] * d);
            }
        }
    }
}

// ------- Aggregation: one wave per dst node, broadcast-index gathers -------
// 64 lanes load esrc[s+base+lane] coalesced (64 edges/batch); indices are
// broadcast to quarters via wave-uniform __shfl (no divergent shfl -- R9
// lesson); validity via mask-multiply fmaf. Quarter q = lane>>4 owns chunk
// [q*clen,(q+1)*clen); feats 8*(l16)..+7 (uint4 = 16 B/lane). Inner loop
// issues 4 independent gathers -> 16 edges in flight per wave.
// R13 lesson: deeper unroll (8) raises VGPR 16->56, halves occupancy, and
// goes issue-bound on mask fmafs -- 4 is the measured sweet spot.

template <int RELU, int OUT_F32>
__global__ __launch_bounds__(256) void agg_kernel(const ushort* __restrict__ H,
                                                  const int* __restrict__ offs,
                                                  const int* __restrict__ esrc,
                                                  const float* __restrict__ dis,
                                                  const float* __restrict__ bias,
                                                  void* __restrict__ OUT, int nnodes) {
    int node = blockIdx.x * 4 + (threadIdx.x >> 6);
    if (node >= nnodes) return;
    int lane = threadIdx.x & 63;
    int q = lane >> 4;
    int l16 = lane & 15;
    int s = offs[node];
    int deg = offs[node + 1] - s;

    float a0 = 0.f, a1 = 0.f, a2 = 0.f, a3 = 0.f;
    float a4 = 0.f, a5 = 0.f, a6 = 0.f, a7 = 0.f;
    float c0 = 0.f, c1 = 0.f, c2 = 0.f, c3 = 0.f;
    float c4 = 0.f, c5 = 0.f, c6 = 0.f, c7 = 0.f;
    const ushort* __restrict__ Hp = H + l16 * 8;

    for (int base = 0; base < deg; base += 64) {
        int rem = deg - base;
        int cnt = (rem < 64) ? rem : 64;
        int idx = (base + lane < deg) ? esrc[s + base + lane] : 0;
        int clen = (cnt + 3) >> 2;        // wave-uniform chunk length (<=16)
        int jbase = q * clen;
        for (int jj = 0; jj < clen; jj += 4) {   // wave-uniform trip count
            int j0 = jbase + jj;
            // all shfls unconditional, all 64 lanes active (4*clen-1 <= 63)
            int s0 = __shfl(idx, j0);
            int s1 = __shfl(idx, j0 + 1);
            int s2 = __shfl(idx, j0 + 2);
            int s3 = __shfl(idx, j0 + 3);
            float m0 = (j0 < cnt) ? 1.f : 0.f;
            float m1 = ((jj + 1 < clen) && (j0 + 1 < cnt)) ? 1.f : 0.f;
            float m2 = ((jj + 2 < clen) && (j0 + 2 < cnt)) ? 1.f : 0.f;
            float m3 = ((jj + 3 < clen) && (j0 + 3 < cnt)) ? 1.f : 0.f;
            uint4 v0 = *(const uint4*)(Hp + (size_t)s0 * DFEAT);
            uint4 v1 = *(const uint4*)(Hp + (size_t)s1 * DFEAT);
            uint4 v2 = *(const uint4*)(Hp + (size_t)s2 * DFEAT);
            uint4 v3 = *(const uint4*)(Hp + (size_t)s3 * DFEAT);
            a0 = fmaf(m0, bf_lo(v0.x), a0); a1 = fmaf(m0, bf_hi(v0.x), a1);
            a2 = fmaf(m0, bf_lo(v0.y), a2); a3 = fmaf(m0, bf_hi(v0.y), a3);
            a4 = fmaf(m0, bf_lo(v0.z), a4); a5 = fmaf(m0, bf_hi(v0.z), a5);
            a6 = fmaf(m0, bf_lo(v0.w), a6); a7 = fmaf(m0, bf_hi(v0.w), a7);
            c0 = fmaf(m1, bf_lo(v1.x), c0); c1 = fmaf(m1, bf_hi(v1.x), c1);
            c2 = fmaf(m1, bf_lo(v1.y), c2); c3 = fmaf(m1, bf_hi(v1.y), c3);
            c4 = fmaf(m1, bf_lo(v1.z), c4); c5 = fmaf(m1, bf_hi(v1.z), c5);
            c6 = fmaf(m1, bf_lo(v1.w), c6); c7 = fmaf(m1, bf_hi(v1.w), c7);
            a0 = fmaf(m2, bf_lo(v2.x), a0); a1 = fmaf(m2, bf_hi(v2.x), a1);
            a2 = fmaf(m2, bf_lo(v2.y), a2); a3 = fmaf(m2, bf_hi(v2.y), a3);
            a4 = fmaf(m2, bf_lo(v2.z), a4); a5 = fmaf(m2, bf_hi(v2.z), a5);
            a6 = fmaf(m2, bf_lo(v2.w), a6); a7 = fmaf(m2, bf_hi(v2.w), a7);
            c0 = fmaf(m3, bf_lo(v3.x), c0); c1 = fmaf(m3, bf_hi(v3.x), c1);
            c2 = fmaf(m3, bf_lo(v3.y), c2); c3 = fmaf(m3, bf_hi(v3.y), c3);
            c4 = fmaf(m3, bf_lo(v3.z), c4); c5 = fmaf(m3, bf_hi(v3.z), c5);
            c6 = fmaf(m3, bf_lo(v3.w), c6); c7 = fmaf(m3, bf_hi(v3.w), c7);
        }
    }
    a0 += c0; a1 += c1; a2 += c2; a3 += c3;
    a4 += c4; a5 += c5; a6 += c6; a7 += c7;

    a0 += __shfl_xor(a0, 16); a1 += __shfl_xor(a1, 16);
    a2 += __shfl_xor(a2, 16); a3 += __shfl_xor(a3, 16);
    a4 += __shfl_xor(a4, 16); a5 += __shfl_xor(a5, 16);
    a6 += __shfl_xor(a6, 16); a7 += __shfl_xor(a7, 16);
    a0 += __shfl_xor(a0, 32); a1 += __shfl_xor(a1, 32);
    a2 += __shfl_xor(a2, 32); a3 += __shfl_xor(a3, 32);
    a4 += __shfl_xor(a4, 32); a5 += __shfl_xor(a5, 32);
    a6 += __shfl_xor(a6, 32); a7 += __shfl_xor(a7, 32);

    float dn = dis[node];
    float4 b0 = *(const float4*)&bias[l16 * 8];
    float4 b1 = *(const float4*)&bias[l16 * 8 + 4];
    float r0 = dn * a0 + b0.x, r1 = dn * a1 + b0.y;
    float r2 = dn * a2 + b0.z, r3 = dn * a3 + b0.w;
    float r4 = dn * a4 + b1.x, r5 = dn * a5 + b1.y;
    float r6 = dn * a6 + b1.z, r7 = dn * a7 + b1.w;
    if (RELU) {
        r0 = fmaxf(r0, 0.f); r1 = fmaxf(r1, 0.f);
        r2 = fmaxf(r2, 0.f); r3 = fmaxf(r3, 0.f);
        r4 = fmaxf(r4, 0.f); r5 = fmaxf(r5, 0.f);
        r6 = fmaxf(r6, 0.f); r7 = fmaxf(r7, 0.f);
    }
    if (q == 0) {
        if (OUT_F32) {
            float* o = (float*)OUT + (size_t)node * DFEAT + l16 * 8;
            *(float4*)o = make_float4(r0, r1, r2, r3);
            *(float4*)(o + 4) = make_float4(r4, r5, r6, r7);
        } else {
            uint4 p;
            p.x = (uint)f2bf(r0) | ((uint)f2bf(r1) << 16);
            p.y = (uint)f2bf(r2) | ((uint)f2bf(r3) << 16);
            p.z = (uint)f2bf(r4) | ((uint)f2bf(r5) << 16);
            p.w = (uint)f2bf(r6) | ((uint)f2bf(r7) << 16);
            *(uint4*)((ushort*)OUT + (size_t)node * DFEAT + l16 * 8) = p;
        }
    }
}

// ---------------- launch ----------------

extern "C" void kernel_launch(void* const* d_in, const int* in_sizes, int n_in,
                              void* d_out, int out_size, void* d_ws, size_t ws_size,
                              hipStream_t stream) {
    const float* x  = (const float*)d_in[0];
    const int*   EI = (const int*)d_in[1];
    const float* W0 = (const float*)d_in[2];
    const float* b0 = (const float*)d_in[3];
    const float* W1 = (const float*)d_in[4];
    const float* b1 = (const float*)d_in[5];
    const float* W2 = (const float*)d_in[6];
    const float* b2 = (const float*)d_in[7];
    float* out = (float*)d_out;

    const int N = in_sizes[0] / DFEAT;
    const int E = in_sizes[1] / 2;
    const int range = (N + RSPLIT - 1) / RSPLIT;
    const int slice = (E + SSPLIT - 1) / SSPLIT;

    // workspace layout (256B aligned)
    char* w = (char*)d_ws;
    auto alloc = [&](size_t bytes) {
        void* p = (void*)w;
        w += (bytes + 255) & ~(size_t)255;
        return p;
    };
    int*    offs  = (int*)alloc((size_t)(N + 1) * 4);
    int*    bsums = (int*)alloc(64 * 4);
    float*  dis   = (float*)alloc((size_t)N * 4);
    ushort* erank = (ushort*)alloc((size_t)E * 2);
    int*    esrc  = (int*)alloc((size_t)E * 4);
    ushort* Wtb   = (ushort*)alloc((size_t)3 * DFEAT * DFEAT * 2);
    ushort* hbuf  = (ushort*)alloc((size_t)N * DFEAT * 2);
    ushort* abuf  = (ushort*)alloc((size_t)N * DFEAT * 2);

    // CSR-build scratch aliased onto hbuf/abuf (dead before gemm/agg run):
    // SSPLIT*N ushorts = 6.4 MB <= N*DFEAT*2 = 12.8 MB.
    ushort* cnt_part = (ushort*)hbuf;   // becomes slice-prefix table after scan1
    ushort* deg_part = (ushort*)abuf;

    const int nb = (N + 1023) / 1024;

    histrank_kernel<<<RSPLIT * SSPLIT, 512, 2 * range * 4, stream>>>(
        EI, cnt_part, deg_part, erank, W0, W1, W2, Wtb, E, N, range, slice);
    scan1_kernel<<<nb, 1024, 0, stream>>>(cnt_part, deg_part, offs, bsums, dis, N);
    scan3_kernel<<<nb, 1024, 0, stream>>>(offs, bsums, N, nb);
    fill_kernel<<<(E + 255) / 256, 256, 0, stream>>>(EI, offs, erank, cnt_part,
                                                     esrc, E, N, slice);

    const int gemmGrid = (N + 127) / 128;
    const int aggGrid  = (N + 3) / 4;

    // layer 0: x(f32) -> hbuf(bf16, dis-scaled) -> abuf(bf16, relu)
    gemm_mfma<1><<<gemmGrid, 256, 0, stream>>>(x, Wtb, dis, hbuf, N);
    agg_kernel<1, 0><<<aggGrid, 256, 0, stream>>>(hbuf, offs, esrc, dis, b0, abuf, N);
    // layer 1
    gemm_mfma<0><<<gemmGrid, 256, 0, stream>>>(abuf, Wtb + DFEAT * DFEAT, dis, hbuf, N);
    agg_kernel<1, 0><<<aggGrid, 256, 0, stream>>>(hbuf, offs, esrc, dis, b1, abuf, N);
    // layer 2: -> d_out (f32, no relu)
    gemm_mfma<0><<<gemmGrid, 256, 0, stream>>>(abuf, Wtb + 2 * DFEAT * DFEAT, dis, hbuf, N);
    agg_kernel<0, 1><<<aggGrid, 256, 0, stream>>>(hbuf, offs, esrc, dis, b2, out, N);
}